// Round 10
// baseline (504.581 us; speedup 1.0000x reference)
//
#include <hip/hip_runtime.h>
#include <math.h>

#define FIN   512
#define H1DIM 256
#define HEADS 4
#define CH    64
#define OUTC  40
#define NEG   0.2f
#define EPSV  1e-16f
#define BK    64

// leaky_relu(a) = max(a, 0.2a)  (valid for all a since 0 < slope < 1): mul+max
__device__ __forceinline__ float leaky(float a) { return fmaxf(a, NEG * a); }

__device__ __forceinline__ short f2bf(float f) {
    unsigned u = __builtin_bit_cast(unsigned, f);
    u += 0x7FFFu + ((u >> 16) & 1u);
    return (short)(u >> 16);
}
__device__ __forceinline__ float bf2f(short s) {
    return __builtin_bit_cast(float, ((unsigned)(unsigned short)s) << 16);
}
// packed f32->bf16 (RNE): 2 elements / instruction
__device__ __forceinline__ unsigned cvtpk(float lo, float hi) {
    unsigned r;
    asm("v_cvt_pk_bf16_f32 %0, %1, %2" : "=v"(r) : "v"(lo), "v"(hi));
    return r;
}

typedef __attribute__((ext_vector_type(2))) float floatx2;

// fp8 (OCP e4m3) HW conversions. Word-select must be an immediate constant.
__device__ __forceinline__ unsigned f32x2_to_fp8x2(float a, float b) {
    return (unsigned)__builtin_amdgcn_cvt_pk_fp8_f32(a, b, 0, false);
}
template <bool HI>
__device__ __forceinline__ floatx2 fp8x2_to_f32(unsigned u) {
    return __builtin_amdgcn_cvt_pk_f32_fp8((int)u, HI);
}

typedef __attribute__((ext_vector_type(8))) short short8;
typedef __attribute__((ext_vector_type(4))) short short4_t;
typedef __attribute__((ext_vector_type(4))) float float4_t;

typedef unsigned int u32;
typedef const __attribute__((address_space(1))) u32 gu32;
typedef __attribute__((address_space(3))) u32 lu32;

__device__ __forceinline__ void load_lds16(const void* g, void* l) {
    __builtin_amdgcn_global_load_lds((gu32*)g, (lu32*)l, 16, 0, 0);
}

// ---------------------------------------------------------------------------
// W1 [512,256] fp32 -> w1t [256,512] bf16 (transposed)
// ---------------------------------------------------------------------------
__global__ void cvt_w1_kernel(const float* __restrict__ W1, short* __restrict__ w1t)
{
    int idx = blockIdx.x * 256 + threadIdx.x;
    if (idx >= FIN * H1DIM) return;
    int k = idx >> 8;
    int n = idx & 255;
    w1t[(size_t)n * FIN + k] = f2bf(W1[idx]);
}

// W2 [256,40] f32 -> w2t [48][256] bf16 (transposed, zero-padded cols 40..47)
__global__ void cvt_w2_kernel(const float* __restrict__ W2, short* __restrict__ w2t)
{
    int idx = blockIdx.x * 256 + threadIdx.x;
    if (idx >= 48 * 256) return;
    int col = idx >> 8;
    int k   = idx & 255;
    float v = (col < OUTC) ? W2[(size_t)k * OUTC + col] : 0.f;
    w2t[idx] = f2bf(v);
}

// ---------------------------------------------------------------------------
// GEMM1 (MFMA bf16) + fused attention scores.
// Coalesced + high-occupancy quadrant: A staged via proven coalesced
// global_load_lds (32 KB only), B read per-lane straight from L2-resident
// w1t (R5-proven neutral vs B-LDS). 5 blocks/CU possible by LDS; target
// >=16 waves/CU so stage-drain of one block hides under compute of others.
// Epilogue bounces fp8 h1 through the A-LDS buffer for coalesced stores.
// ---------------------------------------------------------------------------
__global__ __launch_bounds__(256, 4) void gemm1_mfma_kernel(
    const float* __restrict__ x, const short* __restrict__ w1t,
    const float* __restrict__ attS, const float* __restrict__ attD,
    unsigned char* __restrict__ h1f, float* __restrict__ aS1, float* __restrict__ aD1, int N)
{
    __shared__ float Alf[128 * BK];   // 32KB fp32 A-tile

    const int tid  = threadIdx.x;
    const int lane = tid & 63;
    const int wid  = tid >> 6;
    const int row0 = blockIdx.x * 128;
    const int col0 = wid * 64;
    const int quad = lane >> 4;
    const int m16  = lane & 15;

    const int achunk = ((tid & 15) ^ (tid >> 4)) * 4;
    const float* asrcA[8];
#pragma unroll
    for (int p = 0; p < 8; ++p) {
        int r = row0 + p * 16 + (tid >> 4);
        if (r >= N) r = N - 1;
        asrcA[p] = x + (size_t)r * FIN + achunk;
    }

    // B per-lane direct from L2-resident w1t (R5-proven)
    const short* bp[4];
#pragma unroll
    for (int j = 0; j < 4; ++j)
        bp[j] = w1t + (size_t)(col0 + j * 16 + m16) * FIN + quad * 8;

    float4_t acc[8][4];
#pragma unroll
    for (int i = 0; i < 8; ++i)
#pragma unroll
        for (int j = 0; j < 4; ++j) acc[i][j] = (float4_t){0.f, 0.f, 0.f, 0.f};

    for (int k0 = 0; k0 < FIN; k0 += BK) {
#pragma unroll
        for (int p = 0; p < 8; ++p)
            load_lds16(asrcA[p] + k0, Alf + p * 1024 + tid * 4);

        // B fragments for this K-step (8 x 16B, L2-hit), issued before the
        // barrier so they drain together with the stage
        short8 b[2][4];
#pragma unroll
        for (int half = 0; half < 2; ++half)
#pragma unroll
            for (int j = 0; j < 4; ++j)
                b[half][j] = *(const short8*)(bp[j] + k0 + half * 32);

        __syncthreads();

#pragma unroll
        for (int half = 0; half < 2; ++half) {
#pragma unroll
            for (int i = 0; i < 8; ++i) {
                int row = i * 16 + m16;
                int c0 = (quad + 4 * half) * 2;
                float4 f0 = *(const float4*)&Alf[row * BK + ((c0 ^ m16) * 4)];
                float4 f1 = *(const float4*)&Alf[row * BK + (((c0 + 1) ^ m16) * 4)];
                short8 a;
                unsigned* tp = (unsigned*)&a;
                tp[0] = cvtpk(f0.x, f0.y);
                tp[1] = cvtpk(f0.z, f0.w);
                tp[2] = cvtpk(f1.x, f1.y);
                tp[3] = cvtpk(f1.z, f1.w);
#pragma unroll
                for (int j = 0; j < 4; ++j)
                    acc[i][j] = __builtin_amdgcn_mfma_f32_16x16x32_bf16(a, b[half][j], acc[i][j], 0, 0, 0);
            }
        }
        __syncthreads();
    }

    float attSv[4], attDv[4];
#pragma unroll
    for (int j = 0; j < 4; ++j) {
        attSv[j] = attS[col0 + j * 16 + m16];
        attDv[j] = attD[col0 + j * 16 + m16];
    }

    // epilogue: bounce fp8 through Alf (32 KB = 128 rows x 256 B exactly)
    unsigned char* Bounce = (unsigned char*)Alf;

#pragma unroll
    for (int i = 0; i < 8; ++i) {
#pragma unroll
        for (int r = 0; r < 4; ++r) {
            int rloc = i * 16 + quad * 4 + r;
            unsigned pa = f32x2_to_fp8x2(acc[i][0][r], acc[i][1][r]);
            unsigned pb = f32x2_to_fp8x2(acc[i][2][r], acc[i][3][r]);
            int cb = rloc * 256 + col0 + m16;
            Bounce[cb]      = (unsigned char)(pa & 0xff);
            Bounce[cb + 16] = (unsigned char)((pa >> 8) & 0xff);
            Bounce[cb + 32] = (unsigned char)(pb & 0xff);
            Bounce[cb + 48] = (unsigned char)((pb >> 8) & 0xff);

            float ps = acc[i][0][r] * attSv[0] + acc[i][1][r] * attSv[1]
                     + acc[i][2][r] * attSv[2] + acc[i][3][r] * attSv[3];
            float pd = acc[i][0][r] * attDv[0] + acc[i][1][r] * attDv[1]
                     + acc[i][2][r] * attDv[2] + acc[i][3][r] * attDv[3];
#pragma unroll
            for (int off = 1; off < 16; off <<= 1) {
                ps += __shfl_xor(ps, off);
                pd += __shfl_xor(pd, off);
            }
            int row = row0 + rloc;
            if (m16 == 0 && row < N) {
                aS1[(size_t)row * 4 + wid] = ps;
                aD1[(size_t)row * 4 + wid] = pd;
            }
        }
    }
    __syncthreads();

    // coalesced writeback: 32 KB, 16B/lane full-line stores
#pragma unroll
    for (int inst = 0; inst < 8; ++inst) {
        int flat = inst * 4096 + tid * 16;
        int row  = flat >> 8;
        if (row0 + row < N)
            *(float4*)(h1f + (size_t)row0 * H1DIM + flat) = *(const float4*)(Bounce + flat);
    }
}

// ---------------------------------------------------------------------------
// CSR build. degcount returns per-edge rank (atomic return value) so scatter
// needs no second atomic pass.
// ---------------------------------------------------------------------------
__global__ void degcount_kernel(const int* __restrict__ ei, int* __restrict__ deg,
                                int* __restrict__ rank, int E, int Etot)
{
    int e = blockIdx.x * 256 + threadIdx.x;
    if (e >= Etot) return;
    int d = (e < E) ? ei[E + e] : (e - E);
    rank[e] = atomicAdd(&deg[d], 1);
}

__global__ __launch_bounds__(1024) void scan_partial_kernel(
    const int* __restrict__ deg, int* __restrict__ offsets,
    int* __restrict__ bsums, int N)
{
    __shared__ int wsums[16];
    __shared__ int excl[16];
    int tid = threadIdx.x, lane = tid & 63, wid = tid >> 6;
    int idx = blockIdx.x * 1024 + tid;
    int v = (idx < N) ? deg[idx] : 0;
    int sv = v;
#pragma unroll
    for (int off = 1; off < 64; off <<= 1) {
        int t = __shfl_up(sv, off, 64);
        if (lane >= off) sv += t;
    }
    if (lane == 63) wsums[wid] = sv;
    __syncthreads();
    if (wid == 0 && lane < 16) {
        int wv = wsums[lane];
        int sw = wv;
#pragma unroll
        for (int off = 1; off < 16; off <<= 1) {
            int t = __shfl_up(sw, off, 64);
            if (lane >= off) sw += t;
        }
        excl[lane] = sw - wv;
        if (lane == 15) bsums[blockIdx.x] = sw;
    }
    __syncthreads();
    if (idx < N) offsets[idx + 1] = sv + excl[wid];
}

__global__ __launch_bounds__(1024) void scan_tops_kernel(
    int* __restrict__ bsums, int* __restrict__ boffs, int nb)
{
    __shared__ int wsums[16];
    __shared__ int excl[16];
    int tid = threadIdx.x, lane = tid & 63, wid = tid >> 6;
    int v = (tid < nb) ? bsums[tid] : 0;
    int sv = v;
#pragma unroll
    for (int off = 1; off < 64; off <<= 1) {
        int t = __shfl_up(sv, off, 64);
        if (lane >= off) sv += t;
    }
    if (lane == 63) wsums[wid] = sv;
    __syncthreads();
    if (wid == 0 && lane < 16) {
        int wv = wsums[lane];
        int sw = wv;
#pragma unroll
        for (int off = 1; off < 16; off <<= 1) {
            int t = __shfl_up(sw, off, 64);
            if (lane >= off) sw += t;
        }
        excl[lane] = sw - wv;
    }
    __syncthreads();
    if (tid < nb) boffs[tid] = sv + excl[wid] - v;
}

__global__ __launch_bounds__(1024) void scan_add_kernel(
    int* __restrict__ offsets, const int* __restrict__ boffs, int N)
{
    int idx = blockIdx.x * 1024 + threadIdx.x;
    if (idx == 0) offsets[0] = 0;
    if (idx < N) offsets[idx + 1] += boffs[blockIdx.x];
}

__global__ void scatter_kernel(const int* __restrict__ ei, const int* __restrict__ offsets,
                               const int* __restrict__ rank, int* __restrict__ csr_src,
                               int E, int Etot)
{
    int e = blockIdx.x * 256 + threadIdx.x;
    if (e >= Etot) return;
    int s, d;
    if (e < E) { s = ei[e]; d = ei[E + e]; }
    else       { s = e - E; d = s; }
    csr_src[offsets[d] + rank[e]] = s;
}

// ---------------------------------------------------------------------------
// agg1: fused softmax+gather over fp8 h1 rows (256B each). Wave split into
// two 32-lane halves, each half handles one edge of a pair with 8B/lane
// (uint2) row loads + HW fp8 decode. g1b = ELU(acc/denom + b1), bf16.
// ---------------------------------------------------------------------------
__global__ __launch_bounds__(256) void agg1_kernel(
    const unsigned char* __restrict__ h1f, const float* __restrict__ aS,
    const float* __restrict__ aD, const int* __restrict__ offsets,
    const int* __restrict__ csr_src, const float* __restrict__ b1,
    short* __restrict__ g1b, int N)
{
    int lane = threadIdx.x & 63, wid = threadIdx.x >> 6;
    int half = lane >> 5;          // which edge of the pair this lane serves
    int l32  = lane & 31;
    int n = blockIdx.x * 4 + wid;
    if (n >= N) return;
    int start = offsets[n], end = offsets[n + 1];
    int h = l32 >> 3;              // head = channel/64, 8 channels per lane
    int cbase = l32 * 8;
    float adh = aD[(size_t)n * 4 + h];

    float ac[8];
#pragma unroll
    for (int c = 0; c < 8; ++c) ac[c] = 0.f;
    float denom = 0.f;

    int p = start;
    for (; p + 4 <= end; p += 4) {
        int sA0 = csr_src[p],     sB0 = csr_src[p + 1];
        int sA1 = csr_src[p + 2], sB1 = csr_src[p + 3];
        int s0 = half ? sB0 : sA0;
        int s1 = half ? sB1 : sA1;
        float t0 = aS[(size_t)s0 * 4 + h] + adh;
        float t1 = aS[(size_t)s1 * 4 + h] + adh;
        uint2 r0 = *(const uint2*)&h1f[(size_t)s0 * H1DIM + cbase];
        uint2 r1 = *(const uint2*)&h1f[(size_t)s1 * H1DIM + cbase];
        float w0 = __expf(leaky(t0));
        float w1 = __expf(leaky(t1));
        denom += w0 + w1;
        floatx2 d0a = fp8x2_to_f32<false>(r0.x), d0b = fp8x2_to_f32<true>(r0.x);
        floatx2 d0c = fp8x2_to_f32<false>(r0.y), d0d = fp8x2_to_f32<true>(r0.y);
        floatx2 d1a = fp8x2_to_f32<false>(r1.x), d1b = fp8x2_to_f32<true>(r1.x);
        floatx2 d1c = fp8x2_to_f32<false>(r1.y), d1d = fp8x2_to_f32<true>(r1.y);
        ac[0] += w0 * d0a.x + w1 * d1a.x;
        ac[1] += w0 * d0a.y + w1 * d1a.y;
        ac[2] += w0 * d0b.x + w1 * d1b.x;
        ac[3] += w0 * d0b.y + w1 * d1b.y;
        ac[4] += w0 * d0c.x + w1 * d1c.x;
        ac[5] += w0 * d0c.y + w1 * d1c.y;
        ac[6] += w0 * d0d.x + w1 * d1d.x;
        ac[7] += w0 * d0d.y + w1 * d1d.y;
    }
    for (; p + 2 <= end; p += 2) {
        int sA = csr_src[p], sB = csr_src[p + 1];
        int s = half ? sB : sA;
        float t = aS[(size_t)s * 4 + h] + adh;
        uint2 r = *(const uint2*)&h1f[(size_t)s * H1DIM + cbase];
        float w = __expf(leaky(t));
        denom += w;
        floatx2 da = fp8x2_to_f32<false>(r.x), db = fp8x2_to_f32<true>(r.x);
        floatx2 dc = fp8x2_to_f32<false>(r.y), dd = fp8x2_to_f32<true>(r.y);
        ac[0] += w * da.x; ac[1] += w * da.y;
        ac[2] += w * db.x; ac[3] += w * db.y;
        ac[4] += w * dc.x; ac[5] += w * dc.y;
        ac[6] += w * dd.x; ac[7] += w * dd.y;
    }
    if (p < end) {   // odd tail: both halves read same edge, half 1 gated to 0
        int s = csr_src[p];
        float t = aS[(size_t)s * 4 + h] + adh;
        uint2 r = *(const uint2*)&h1f[(size_t)s * H1DIM + cbase];
        float w = half ? 0.f : __expf(leaky(t));
        denom += w;
        floatx2 da = fp8x2_to_f32<false>(r.x), db = fp8x2_to_f32<true>(r.x);
        floatx2 dc = fp8x2_to_f32<false>(r.y), dd = fp8x2_to_f32<true>(r.y);
        ac[0] += w * da.x; ac[1] += w * da.y;
        ac[2] += w * db.x; ac[3] += w * db.y;
        ac[4] += w * dc.x; ac[5] += w * dc.y;
        ac[6] += w * dd.x; ac[7] += w * dd.y;
    }

    // combine the two half-wave partial sums
    denom += __shfl_xor(denom, 32);
#pragma unroll
    for (int c = 0; c < 8; ++c) ac[c] += __shfl_xor(ac[c], 32);

    if (half == 0) {
        float inv = 1.f / (denom + EPSV);
        float4 b0 = *(const float4*)&b1[cbase];
        float4 b4 = *(const float4*)&b1[cbase + 4];
        float v[8];
        v[0] = ac[0] * inv + b0.x;
        v[1] = ac[1] * inv + b0.y;
        v[2] = ac[2] * inv + b0.z;
        v[3] = ac[3] * inv + b0.w;
        v[4] = ac[4] * inv + b4.x;
        v[5] = ac[5] * inv + b4.y;
        v[6] = ac[6] * inv + b4.z;
        v[7] = ac[7] * inv + b4.w;
#pragma unroll
        for (int c = 0; c < 8; ++c) v[c] = v[c] > 0.f ? v[c] : expm1f(v[c]);
        short8 o;
        unsigned* op = (unsigned*)&o;
        op[0] = cvtpk(v[0], v[1]);
        op[1] = cvtpk(v[2], v[3]);
        op[2] = cvtpk(v[4], v[5]);
        op[3] = cvtpk(v[6], v[7]);
        *(short8*)&g1b[(size_t)n * H1DIM + cbase] = o;
    }
}

// ---------------------------------------------------------------------------
// GEMM2 (MFMA bf16): h2b[N,40] = g1[N,256] @ W2; fused a_src2/a_dst2.
// ---------------------------------------------------------------------------
__global__ __launch_bounds__(256, 4) void gemm2_kernel(
    const short* __restrict__ g1b, const short* __restrict__ w2t,
    const float* __restrict__ attS2, const float* __restrict__ attD2,
    short* __restrict__ h2b, float* __restrict__ aS2, float* __restrict__ aD2, int N)
{
    __shared__ short As[64 * 256];   // 32 KB bf16 A-tile, chunk-swizzled

    const int tid  = threadIdx.x;
    const int lane = tid & 63;
    const int wid  = tid >> 6;
    const int row0 = blockIdx.x * 64;
    const int quad = lane >> 4;
    const int m16  = lane & 15;

    // stage: 8 x 16B per thread; source chunk XOR-swizzled so the strided
    // column reads below are conflict-free (LDS dest stays linear)
#pragma unroll
    for (int p = 0; p < 8; ++p) {
        int f    = p * 256 + tid;        // 16B-chunk index 0..2047
        int row  = f >> 5;               // 32 chunks per row
        int cpos = f & 31;
        int csrc = cpos ^ (row & 15);
        int gr = row0 + row; if (gr >= N) gr = N - 1;
        load_lds16(g1b + (size_t)gr * H1DIM + csrc * 8, (char*)As + (size_t)f * 16);
    }
    __syncthreads();

    const short* bp[3];
#pragma unroll
    for (int j = 0; j < 3; ++j)
        bp[j] = w2t + (j * 16 + m16) * 256 + quad * 8;

    float4_t acc[3];
#pragma unroll
    for (int j = 0; j < 3; ++j) acc[j] = (float4_t){0.f, 0.f, 0.f, 0.f};

    const int wrow = wid * 16;
#pragma unroll
    for (int kk = 0; kk < 8; ++kk) {
        short8 a = *(const short8*)&As[(wrow + m16) * 256 + (((kk * 4 + quad) ^ m16) * 8)];
        short8 b0 = *(const short8*)(bp[0] + kk * 32);
        short8 b1v = *(const short8*)(bp[1] + kk * 32);
        short8 b2v = *(const short8*)(bp[2] + kk * 32);
        acc[0] = __builtin_amdgcn_mfma_f32_16x16x32_bf16(a, b0, acc[0], 0, 0, 0);
        acc[1] = __builtin_amdgcn_mfma_f32_16x16x32_bf16(a, b1v, acc[1], 0, 0, 0);
        acc[2] = __builtin_amdgcn_mfma_f32_16x16x32_bf16(a, b2v, acc[2], 0, 0, 0);
    }

    float attSv[3], attDv[3];
#pragma unroll
    for (int j = 0; j < 3; ++j) {
        int col = j * 16 + m16;
        attSv[j] = (col < OUTC) ? attS2[col] : 0.f;
        attDv[j] = (col < OUTC) ? attD2[col] : 0.f;
    }

#pragma unroll
    for (int r = 0; r < 4; ++r) {
        int rowg = row0 + wrow + quad * 4 + r;
        if (rowg < N) {
#pragma unroll
            for (int j = 0; j < 3; ++j) {
                int col = j * 16 + m16;
                if (col < OUTC)
                    h2b[(size_t)rowg * OUTC + col] = f2bf(acc[j][r]);
            }
        }
        float ps = acc[0][r] * attSv[0] + acc[1][r] * attSv[1] + acc[2][r] * attSv[2];
        float pd = acc[0][r] * attDv[0] + acc[1][r] * attDv[1] + acc[2][r] * attDv[2];
#pragma unroll
        for (int off = 1; off < 16; off <<= 1) {
            ps += __shfl_xor(ps, off);
            pd += __shfl_xor(pd, off);
        }
        if (m16 == 0 && rowg < N) { aS2[rowg] = ps; aD2[rowg] = pd; }
    }
}

// ---------------------------------------------------------------------------
// agg2: fused softmax+gather (H=1) + bias + log_softmax
// ---------------------------------------------------------------------------
__global__ __launch_bounds__(256) void agg2_kernel(
    const short* __restrict__ h2b, const float* __restrict__ aS2,
    const float* __restrict__ aD2, const int* __restrict__ offsets,
    const int* __restrict__ csr_src, const float* __restrict__ b2,
    float* __restrict__ out, int N)
{
    int lane = threadIdx.x & 63, wid = threadIdx.x >> 6;
    int n = blockIdx.x * 4 + wid;
    if (n >= N) return;
    int start = offsets[n], end = offsets[n + 1];
    bool act = lane < OUTC;
    int cc = act ? lane : 0;
    float ad = aD2[n];

    float acc = 0.f, denom = 0.f;
    int p = start;
    for (; p + 4 <= end; p += 4) {
        int s0 = csr_src[p], s1 = csr_src[p + 1], s2 = csr_src[p + 2], s3 = csr_src[p + 3];
        float w0 = __expf(leaky(aS2[s0] + ad));
        float w1 = __expf(leaky(aS2[s1] + ad));
        float w2 = __expf(leaky(aS2[s2] + ad));
        float w3 = __expf(leaky(aS2[s3] + ad));
        short v0 = h2b[(size_t)s0 * OUTC + cc];
        short v1 = h2b[(size_t)s1 * OUTC + cc];
        short v2 = h2b[(size_t)s2 * OUTC + cc];
        short v3 = h2b[(size_t)s3 * OUTC + cc];
        denom += w0 + w1 + w2 + w3;
        acc += w0 * bf2f(v0) + w1 * bf2f(v1) + w2 * bf2f(v2) + w3 * bf2f(v3);
    }
    for (; p < end; ++p) {
        int s = csr_src[p];
        float w = __expf(leaky(aS2[s] + ad));
        denom += w;
        acc += w * bf2f(h2b[(size_t)s * OUTC + cc]);
    }

    float v = acc / (denom + EPSV) + (act ? b2[lane] : 0.f);

    float vm = act ? v : -INFINITY;
#pragma unroll
    for (int off = 32; off > 0; off >>= 1) vm = fmaxf(vm, __shfl_xor(vm, off));
    float ex2 = act ? __expf(v - vm) : 0.f;
    float tot = ex2;
#pragma unroll
    for (int off = 32; off > 0; off >>= 1) tot += __shfl_xor(tot, off);
    float res = v - vm - __logf(tot);
    if (act) out[(size_t)n * OUTC + lane] = res;
}

// ---------------------------------------------------------------------------
extern "C" void kernel_launch(void* const* d_in, const int* in_sizes, int n_in,
                              void* d_out, int out_size, void* d_ws, size_t ws_size,
                              hipStream_t stream)
{
    const float* x     = (const float*)d_in[0];
    const int*   ei    = (const int*)d_in[1];
    const float* W1    = (const float*)d_in[2];
    const float* attS1 = (const float*)d_in[3];
    const float* attD1 = (const float*)d_in[4];
    const float* b1    = (const float*)d_in[5];
    const float* W2    = (const float*)d_in[6];
    const float* attS2 = (const float*)d_in[7];
    const float* attD2 = (const float*)d_in[8];
    const float* b2    = (const float*)d_in[9];
    float* out = (float*)d_out;

    const int N    = in_sizes[0] / FIN;
    const int E    = in_sizes[1] / 2;
    const int Etot = E + N;
    const int nb   = (N + 1023) / 1024;

    char* ws = (char*)d_ws;
    size_t off = 0;
    auto take = [&](size_t bytes) -> char* {
        char* p = ws + off;
        off = (off + bytes + 255) & ~(size_t)255;
        return p;
    };
    unsigned char* h1f = (unsigned char*)take((size_t)N * H1DIM);
    short* g1b     = (short*)take((size_t)N * H1DIM * 2);
    short* w1t     = (short*)take((size_t)FIN * H1DIM * 2);
    short* w2t     = (short*)take((size_t)48 * 256 * 2);
    float* aS1     = (float*)take((size_t)N * 4 * 4);
    float* aD1     = (float*)take((size_t)N * 4 * 4);
    short* h2b     = (short*)take((size_t)N * OUTC * 2);
    float* aS2v    = (float*)take((size_t)N * 4);
    float* aD2v    = (float*)take((size_t)N * 4);
    int*   deg     = (int*)take((size_t)N * 4);
    int*   offsets = (int*)take((size_t)(N + 1) * 4);
    int*   bsums   = (int*)take((size_t)nb * 4);
    int*   boffs   = (int*)take((size_t)nb * 4);
    int*   rank    = (int*)take((size_t)Etot * 4);
    int*   csr_src = (int*)take((size_t)Etot * 4);

    (void)hipMemsetAsync(deg, 0, (size_t)N * 4, stream);

    cvt_w1_kernel<<<(FIN * H1DIM + 255) / 256, 256, 0, stream>>>(W1, w1t);
    cvt_w2_kernel<<<48, 256, 0, stream>>>(W2, w2t);
    gemm1_mfma_kernel<<<(N + 127) / 128, 256, 0, stream>>>(x, w1t, attS1, attD1, h1f, aS1, aD1, N);
    degcount_kernel<<<(Etot + 255) / 256, 256, 0, stream>>>(ei, deg, rank, E, Etot);
    scan_partial_kernel<<<nb, 1024, 0, stream>>>(deg, offsets, bsums, N);
    scan_tops_kernel<<<1, 1024, 0, stream>>>(bsums, boffs, nb);
    scan_add_kernel<<<nb, 1024, 0, stream>>>(offsets, boffs, N);
    scatter_kernel<<<(Etot + 255) / 256, 256, 0, stream>>>(ei, offsets, rank, csr_src, E, Etot);
    agg1_kernel<<<(N + 3) / 4, 256, 0, stream>>>(h1f, aS1, aD1, offsets, csr_src, b1, g1b, N);
    gemm2_kernel<<<(N + 63) / 64, 256, 0, stream>>>(g1b, w2t, attS2, attD2, h2b, aS2v, aD2v, N);
    agg2_kernel<<<(N + 3) / 4, 256, 0, stream>>>(h2b, aS2v, aD2v, offsets, csr_src, b2, out, N);
}

// Round 11
// 353.592 us; speedup vs baseline: 1.4270x; 1.4270x over previous
//
#include <hip/hip_runtime.h>
#include <math.h>

#define FIN   512
#define H1DIM 256
#define HEADS 4
#define CH    64
#define OUTC  40
#define NEG   0.2f
#define EPSV  1e-16f
#define BK    64

// leaky_relu(a) = max(a, 0.2a)  (valid for all a since 0 < slope < 1): mul+max
__device__ __forceinline__ float leaky(float a) { return fmaxf(a, NEG * a); }

__device__ __forceinline__ short f2bf(float f) {
    unsigned u = __builtin_bit_cast(unsigned, f);
    u += 0x7FFFu + ((u >> 16) & 1u);
    return (short)(u >> 16);
}
__device__ __forceinline__ float bf2f(short s) {
    return __builtin_bit_cast(float, ((unsigned)(unsigned short)s) << 16);
}
// packed f32->bf16 (RNE): 2 elements / instruction
__device__ __forceinline__ unsigned cvtpk(float lo, float hi) {
    unsigned r;
    asm("v_cvt_pk_bf16_f32 %0, %1, %2" : "=v"(r) : "v"(lo), "v"(hi));
    return r;
}

typedef __attribute__((ext_vector_type(2))) float floatx2;

// fp8 (OCP e4m3) HW conversions. Word-select must be an immediate constant.
__device__ __forceinline__ unsigned f32x2_to_fp8x2(float a, float b) {
    return (unsigned)__builtin_amdgcn_cvt_pk_fp8_f32(a, b, 0, false);
}
template <bool HI>
__device__ __forceinline__ floatx2 fp8x2_to_f32(unsigned u) {
    return __builtin_amdgcn_cvt_pk_f32_fp8((int)u, HI);
}
__device__ __forceinline__ float fp8_to_f32(unsigned char b) {
    return fp8x2_to_f32<false>((unsigned)b).x;
}

typedef __attribute__((ext_vector_type(8))) short short8;
typedef __attribute__((ext_vector_type(4))) short short4_t;
typedef __attribute__((ext_vector_type(4))) float float4_t;

typedef unsigned int u32;
typedef const __attribute__((address_space(1))) u32 gu32;
typedef __attribute__((address_space(3))) u32 lu32;

__device__ __forceinline__ void load_lds16(const void* g, void* l) {
    __builtin_amdgcn_global_load_lds((gu32*)g, (lu32*)l, 16, 0, 0);
}

// ---------------------------------------------------------------------------
// W1 [512,256] fp32 -> w1t [256,512] bf16 (transposed)
// ---------------------------------------------------------------------------
__global__ void cvt_w1_kernel(const float* __restrict__ W1, short* __restrict__ w1t)
{
    int idx = blockIdx.x * 256 + threadIdx.x;
    if (idx >= FIN * H1DIM) return;
    int k = idx >> 8;
    int n = idx & 255;
    w1t[(size_t)n * FIN + k] = f2bf(W1[idx]);
}

// W2 [256,40] f32 -> w2t [48][256] bf16 (transposed, zero-padded cols 40..47)
__global__ void cvt_w2_kernel(const float* __restrict__ W2, short* __restrict__ w2t)
{
    int idx = blockIdx.x * 256 + threadIdx.x;
    if (idx >= 48 * 256) return;
    int col = idx >> 8;
    int k   = idx & 255;
    float v = (col < OUTC) ? W2[(size_t)k * OUTC + col] : 0.f;
    w2t[idx] = f2bf(v);
}

// ---------------------------------------------------------------------------
// GEMM1 (MFMA bf16) + fused attention scores. R8/R9-proven exact version:
// coalesced global_load_lds staging of A fp32 + B bf16, 2-barrier K-loop,
// 128-row tile, launch_bounds(256,2) (VGPR 108, no spill).
// Epilogue bounces fp8 h1 through the A-LDS buffer for coalesced stores.
// ---------------------------------------------------------------------------
__global__ __launch_bounds__(256, 2) void gemm1_mfma_kernel(
    const float* __restrict__ x, const short* __restrict__ w1t,
    const float* __restrict__ attS, const float* __restrict__ attD,
    unsigned char* __restrict__ h1f, float* __restrict__ aS1, float* __restrict__ aD1, int N)
{
    __shared__ float Alf[128 * BK];   // 32KB fp32 A-tile
    __shared__ short Bls[256 * BK];   // 32KB bf16 B-tile

    const int tid  = threadIdx.x;
    const int lane = tid & 63;
    const int wid  = tid >> 6;
    const int row0 = blockIdx.x * 128;
    const int col0 = wid * 64;
    const int quad = lane >> 4;
    const int m16  = lane & 15;

    const int achunk = ((tid & 15) ^ (tid >> 4)) * 4;
    const float* asrcA[8];
#pragma unroll
    for (int p = 0; p < 8; ++p) {
        int r = row0 + p * 16 + (tid >> 4);
        if (r >= N) r = N - 1;
        asrcA[p] = x + (size_t)r * FIN + achunk;
    }

    const int trow = tid >> 3;
    const int bswz = ((tid & 7) ^ (trow & 7)) * 8;
    const short* bsrc[8];
#pragma unroll
    for (int p = 0; p < 8; ++p)
        bsrc[p] = w1t + (size_t)(p * 32 + trow) * FIN + bswz;

    float4_t acc[8][4];
#pragma unroll
    for (int i = 0; i < 8; ++i)
#pragma unroll
        for (int j = 0; j < 4; ++j) acc[i][j] = (float4_t){0.f, 0.f, 0.f, 0.f};

    const int swzB = (m16 & 7);

    for (int k0 = 0; k0 < FIN; k0 += BK) {
#pragma unroll
        for (int p = 0; p < 8; ++p)
            load_lds16(asrcA[p] + k0, Alf + p * 1024 + tid * 4);
#pragma unroll
        for (int p = 0; p < 8; ++p)
            load_lds16(bsrc[p] + k0, Bls + p * 2048 + tid * 8);
        __syncthreads();

#pragma unroll
        for (int half = 0; half < 2; ++half) {
            short8 b[4];
#pragma unroll
            for (int j = 0; j < 4; ++j) {
                int col = col0 + j * 16 + m16;
                int sub = (quad + 4 * half) ^ swzB;
                b[j] = *(const short8*)&Bls[col * BK + sub * 8];
            }
#pragma unroll
            for (int i = 0; i < 8; ++i) {
                int row = i * 16 + m16;
                int c0 = (quad + 4 * half) * 2;
                float4 f0 = *(const float4*)&Alf[row * BK + ((c0 ^ m16) * 4)];
                float4 f1 = *(const float4*)&Alf[row * BK + (((c0 + 1) ^ m16) * 4)];
                short8 a;
                unsigned* tp = (unsigned*)&a;
                tp[0] = cvtpk(f0.x, f0.y);
                tp[1] = cvtpk(f0.z, f0.w);
                tp[2] = cvtpk(f1.x, f1.y);
                tp[3] = cvtpk(f1.z, f1.w);
#pragma unroll
                for (int j = 0; j < 4; ++j)
                    acc[i][j] = __builtin_amdgcn_mfma_f32_16x16x32_bf16(a, b[j], acc[i][j], 0, 0, 0);
            }
        }
        __syncthreads();
    }

    float attSv[4], attDv[4];
#pragma unroll
    for (int j = 0; j < 4; ++j) {
        attSv[j] = attS[col0 + j * 16 + m16];
        attDv[j] = attD[col0 + j * 16 + m16];
    }

    // epilogue: bounce fp8 through Alf (32 KB = 128 rows x 256 B exactly)
    unsigned char* Bounce = (unsigned char*)Alf;

#pragma unroll
    for (int i = 0; i < 8; ++i) {
#pragma unroll
        for (int r = 0; r < 4; ++r) {
            int rloc = i * 16 + quad * 4 + r;
            unsigned pa = f32x2_to_fp8x2(acc[i][0][r], acc[i][1][r]);
            unsigned pb = f32x2_to_fp8x2(acc[i][2][r], acc[i][3][r]);
            int cb = rloc * 256 + col0 + m16;
            Bounce[cb]      = (unsigned char)(pa & 0xff);
            Bounce[cb + 16] = (unsigned char)((pa >> 8) & 0xff);
            Bounce[cb + 32] = (unsigned char)(pb & 0xff);
            Bounce[cb + 48] = (unsigned char)((pb >> 8) & 0xff);

            float ps = acc[i][0][r] * attSv[0] + acc[i][1][r] * attSv[1]
                     + acc[i][2][r] * attSv[2] + acc[i][3][r] * attSv[3];
            float pd = acc[i][0][r] * attDv[0] + acc[i][1][r] * attDv[1]
                     + acc[i][2][r] * attDv[2] + acc[i][3][r] * attDv[3];
#pragma unroll
            for (int off = 1; off < 16; off <<= 1) {
                ps += __shfl_xor(ps, off);
                pd += __shfl_xor(pd, off);
            }
            int row = row0 + rloc;
            if (m16 == 0 && row < N) {
                aS1[(size_t)row * 4 + wid] = ps;
                aD1[(size_t)row * 4 + wid] = pd;
            }
        }
    }
    __syncthreads();

    // coalesced writeback: 32 KB, 16B/lane full-line stores
#pragma unroll
    for (int inst = 0; inst < 8; ++inst) {
        int flat = inst * 4096 + tid * 16;
        int row  = flat >> 8;
        if (row0 + row < N)
            *(float4*)(h1f + (size_t)row0 * H1DIM + flat) = *(const float4*)(Bounce + flat);
    }
}

// ---------------------------------------------------------------------------
// CSR build. degcount returns per-edge rank (atomic return value) so scatter
// needs no second atomic pass.
// ---------------------------------------------------------------------------
__global__ void degcount_kernel(const int* __restrict__ ei, int* __restrict__ deg,
                                int* __restrict__ rank, int E, int Etot)
{
    int e = blockIdx.x * 256 + threadIdx.x;
    if (e >= Etot) return;
    int d = (e < E) ? ei[E + e] : (e - E);
    rank[e] = atomicAdd(&deg[d], 1);
}

__global__ __launch_bounds__(1024) void scan_partial_kernel(
    const int* __restrict__ deg, int* __restrict__ offsets,
    int* __restrict__ bsums, int N)
{
    __shared__ int wsums[16];
    __shared__ int excl[16];
    int tid = threadIdx.x, lane = tid & 63, wid = tid >> 6;
    int idx = blockIdx.x * 1024 + tid;
    int v = (idx < N) ? deg[idx] : 0;
    int sv = v;
#pragma unroll
    for (int off = 1; off < 64; off <<= 1) {
        int t = __shfl_up(sv, off, 64);
        if (lane >= off) sv += t;
    }
    if (lane == 63) wsums[wid] = sv;
    __syncthreads();
    if (wid == 0 && lane < 16) {
        int wv = wsums[lane];
        int sw = wv;
#pragma unroll
        for (int off = 1; off < 16; off <<= 1) {
            int t = __shfl_up(sw, off, 64);
            if (lane >= off) sw += t;
        }
        excl[lane] = sw - wv;
        if (lane == 15) bsums[blockIdx.x] = sw;
    }
    __syncthreads();
    if (idx < N) offsets[idx + 1] = sv + excl[wid];
}

__global__ __launch_bounds__(1024) void scan_tops_kernel(
    int* __restrict__ bsums, int* __restrict__ boffs, int nb)
{
    __shared__ int wsums[16];
    __shared__ int excl[16];
    int tid = threadIdx.x, lane = tid & 63, wid = tid >> 6;
    int v = (tid < nb) ? bsums[tid] : 0;
    int sv = v;
#pragma unroll
    for (int off = 1; off < 64; off <<= 1) {
        int t = __shfl_up(sv, off, 64);
        if (lane >= off) sv += t;
    }
    if (lane == 63) wsums[wid] = sv;
    __syncthreads();
    if (wid == 0 && lane < 16) {
        int wv = wsums[lane];
        int sw = wv;
#pragma unroll
        for (int off = 1; off < 16; off <<= 1) {
            int t = __shfl_up(sw, off, 64);
            if (lane >= off) sw += t;
        }
        excl[lane] = sw - wv;
    }
    __syncthreads();
    if (tid < nb) boffs[tid] = sv + excl[wid] - v;
}

__global__ __launch_bounds__(1024) void scan_add_kernel(
    int* __restrict__ offsets, const int* __restrict__ boffs, int N)
{
    int idx = blockIdx.x * 1024 + threadIdx.x;
    if (idx == 0) offsets[0] = 0;
    if (idx < N) offsets[idx + 1] += boffs[blockIdx.x];
}

__global__ void scatter_kernel(const int* __restrict__ ei, const int* __restrict__ offsets,
                               const int* __restrict__ rank, int* __restrict__ csr_src,
                               int E, int Etot)
{
    int e = blockIdx.x * 256 + threadIdx.x;
    if (e >= Etot) return;
    int s, d;
    if (e < E) { s = ei[e]; d = ei[E + e]; }
    else       { s = e - E; d = s; }
    csr_src[offsets[d] + rank[e]] = s;
}

// ---------------------------------------------------------------------------
// agg1: fused softmax+gather over fp8 h1 rows (256B each). Wave split into
// two 32-lane halves, each half handles one edge of a pair with 8B/lane
// (uint2) row loads + HW fp8 decode. g1b = ELU(acc/denom + b1), bf16.
// ---------------------------------------------------------------------------
__global__ __launch_bounds__(256) void agg1_kernel(
    const unsigned char* __restrict__ h1f, const float* __restrict__ aS,
    const float* __restrict__ aD, const int* __restrict__ offsets,
    const int* __restrict__ csr_src, const float* __restrict__ b1,
    short* __restrict__ g1b, int N)
{
    int lane = threadIdx.x & 63, wid = threadIdx.x >> 6;
    int half = lane >> 5;          // which edge of the pair this lane serves
    int l32  = lane & 31;
    int n = blockIdx.x * 4 + wid;
    if (n >= N) return;
    int start = offsets[n], end = offsets[n + 1];
    int h = l32 >> 3;              // head = channel/64, 8 channels per lane
    int cbase = l32 * 8;
    float adh = aD[(size_t)n * 4 + h];

    float ac[8];
#pragma unroll
    for (int c = 0; c < 8; ++c) ac[c] = 0.f;
    float denom = 0.f;

    int p = start;
    for (; p + 4 <= end; p += 4) {
        int sA0 = csr_src[p],     sB0 = csr_src[p + 1];
        int sA1 = csr_src[p + 2], sB1 = csr_src[p + 3];
        int s0 = half ? sB0 : sA0;
        int s1 = half ? sB1 : sA1;
        float t0 = aS[(size_t)s0 * 4 + h] + adh;
        float t1 = aS[(size_t)s1 * 4 + h] + adh;
        uint2 r0 = *(const uint2*)&h1f[(size_t)s0 * H1DIM + cbase];
        uint2 r1 = *(const uint2*)&h1f[(size_t)s1 * H1DIM + cbase];
        float w0 = __expf(leaky(t0));
        float w1 = __expf(leaky(t1));
        denom += w0 + w1;
        floatx2 d0a = fp8x2_to_f32<false>(r0.x), d0b = fp8x2_to_f32<true>(r0.x);
        floatx2 d0c = fp8x2_to_f32<false>(r0.y), d0d = fp8x2_to_f32<true>(r0.y);
        floatx2 d1a = fp8x2_to_f32<false>(r1.x), d1b = fp8x2_to_f32<true>(r1.x);
        floatx2 d1c = fp8x2_to_f32<false>(r1.y), d1d = fp8x2_to_f32<true>(r1.y);
        ac[0] += w0 * d0a.x + w1 * d1a.x;
        ac[1] += w0 * d0a.y + w1 * d1a.y;
        ac[2] += w0 * d0b.x + w1 * d1b.x;
        ac[3] += w0 * d0b.y + w1 * d1b.y;
        ac[4] += w0 * d0c.x + w1 * d1c.x;
        ac[5] += w0 * d0c.y + w1 * d1c.y;
        ac[6] += w0 * d0d.x + w1 * d1d.x;
        ac[7] += w0 * d0d.y + w1 * d1d.y;
    }
    for (; p + 2 <= end; p += 2) {
        int sA = csr_src[p], sB = csr_src[p + 1];
        int s = half ? sB : sA;
        float t = aS[(size_t)s * 4 + h] + adh;
        uint2 r = *(const uint2*)&h1f[(size_t)s * H1DIM + cbase];
        float w = __expf(leaky(t));
        denom += w;
        floatx2 da = fp8x2_to_f32<false>(r.x), db = fp8x2_to_f32<true>(r.x);
        floatx2 dc = fp8x2_to_f32<false>(r.y), dd = fp8x2_to_f32<true>(r.y);
        ac[0] += w * da.x; ac[1] += w * da.y;
        ac[2] += w * db.x; ac[3] += w * db.y;
        ac[4] += w * dc.x; ac[5] += w * dc.y;
        ac[6] += w * dd.x; ac[7] += w * dd.y;
    }
    if (p < end) {   // odd tail: both halves read same edge, half 1 gated to 0
        int s = csr_src[p];
        float t = aS[(size_t)s * 4 + h] + adh;
        uint2 r = *(const uint2*)&h1f[(size_t)s * H1DIM + cbase];
        float w = half ? 0.f : __expf(leaky(t));
        denom += w;
        floatx2 da = fp8x2_to_f32<false>(r.x), db = fp8x2_to_f32<true>(r.x);
        floatx2 dc = fp8x2_to_f32<false>(r.y), dd = fp8x2_to_f32<true>(r.y);
        ac[0] += w * da.x; ac[1] += w * da.y;
        ac[2] += w * db.x; ac[3] += w * db.y;
        ac[4] += w * dc.x; ac[5] += w * dc.y;
        ac[6] += w * dd.x; ac[7] += w * dd.y;
    }

    // combine the two half-wave partial sums
    denom += __shfl_xor(denom, 32);
#pragma unroll
    for (int c = 0; c < 8; ++c) ac[c] += __shfl_xor(ac[c], 32);

    if (half == 0) {
        float inv = 1.f / (denom + EPSV);
        float4 b0 = *(const float4*)&b1[cbase];
        float4 b4 = *(const float4*)&b1[cbase + 4];
        float v[8];
        v[0] = ac[0] * inv + b0.x;
        v[1] = ac[1] * inv + b0.y;
        v[2] = ac[2] * inv + b0.z;
        v[3] = ac[3] * inv + b0.w;
        v[4] = ac[4] * inv + b4.x;
        v[5] = ac[5] * inv + b4.y;
        v[6] = ac[6] * inv + b4.z;
        v[7] = ac[7] * inv + b4.w;
#pragma unroll
        for (int c = 0; c < 8; ++c) v[c] = v[c] > 0.f ? v[c] : expm1f(v[c]);
        short8 o;
        unsigned* op = (unsigned*)&o;
        op[0] = cvtpk(v[0], v[1]);
        op[1] = cvtpk(v[2], v[3]);
        op[2] = cvtpk(v[4], v[5]);
        op[3] = cvtpk(v[6], v[7]);
        *(short8*)&g1b[(size_t)n * H1DIM + cbase] = o;
    }
}

// ---------------------------------------------------------------------------
// GEMM2 (MFMA bf16): h2f[N,40] fp8 = g1[N,256] @ W2; fused a_src2/a_dst2.
// h2 stored fp8 e4m3: shrinks h2 to 2 MB -> L2-resident in EVERY XCD, so
// agg2's random gathers become L2 hits (same mechanism as the agg1 fp8 win).
// ---------------------------------------------------------------------------
__global__ __launch_bounds__(256, 4) void gemm2_kernel(
    const short* __restrict__ g1b, const short* __restrict__ w2t,
    const float* __restrict__ attS2, const float* __restrict__ attD2,
    unsigned char* __restrict__ h2f, float* __restrict__ aS2, float* __restrict__ aD2, int N)
{
    __shared__ short As[64 * 256];   // 32 KB bf16 A-tile, chunk-swizzled

    const int tid  = threadIdx.x;
    const int lane = tid & 63;
    const int wid  = tid >> 6;
    const int row0 = blockIdx.x * 64;
    const int quad = lane >> 4;
    const int m16  = lane & 15;

    // stage: 8 x 16B per thread; source chunk XOR-swizzled so the strided
    // column reads below are conflict-free (LDS dest stays linear)
#pragma unroll
    for (int p = 0; p < 8; ++p) {
        int f    = p * 256 + tid;        // 16B-chunk index 0..2047
        int row  = f >> 5;               // 32 chunks per row
        int cpos = f & 31;
        int csrc = cpos ^ (row & 15);
        int gr = row0 + row; if (gr >= N) gr = N - 1;
        load_lds16(g1b + (size_t)gr * H1DIM + csrc * 8, (char*)As + (size_t)f * 16);
    }
    __syncthreads();

    const short* bp[3];
#pragma unroll
    for (int j = 0; j < 3; ++j)
        bp[j] = w2t + (j * 16 + m16) * 256 + quad * 8;

    float4_t acc[3];
#pragma unroll
    for (int j = 0; j < 3; ++j) acc[j] = (float4_t){0.f, 0.f, 0.f, 0.f};

    const int wrow = wid * 16;
#pragma unroll
    for (int kk = 0; kk < 8; ++kk) {
        short8 a = *(const short8*)&As[(wrow + m16) * 256 + (((kk * 4 + quad) ^ m16) * 8)];
        short8 b0 = *(const short8*)(bp[0] + kk * 32);
        short8 b1v = *(const short8*)(bp[1] + kk * 32);
        short8 b2v = *(const short8*)(bp[2] + kk * 32);
        acc[0] = __builtin_amdgcn_mfma_f32_16x16x32_bf16(a, b0, acc[0], 0, 0, 0);
        acc[1] = __builtin_amdgcn_mfma_f32_16x16x32_bf16(a, b1v, acc[1], 0, 0, 0);
        acc[2] = __builtin_amdgcn_mfma_f32_16x16x32_bf16(a, b2v, acc[2], 0, 0, 0);
    }

    float attSv[3], attDv[3];
#pragma unroll
    for (int j = 0; j < 3; ++j) {
        int col = j * 16 + m16;
        attSv[j] = (col < OUTC) ? attS2[col] : 0.f;
        attDv[j] = (col < OUTC) ? attD2[col] : 0.f;
    }

#pragma unroll
    for (int r = 0; r < 4; ++r) {
        int rowg = row0 + wrow + quad * 4 + r;
        if (rowg < N) {
#pragma unroll
            for (int j = 0; j < 3; ++j) {
                int col = j * 16 + m16;
                if (col < OUTC)
                    h2f[(size_t)rowg * OUTC + col] =
                        (unsigned char)(f32x2_to_fp8x2(acc[j][r], 0.f) & 0xff);
            }
        }
        float ps = acc[0][r] * attSv[0] + acc[1][r] * attSv[1] + acc[2][r] * attSv[2];
        float pd = acc[0][r] * attDv[0] + acc[1][r] * attDv[1] + acc[2][r] * attDv[2];
#pragma unroll
        for (int off = 1; off < 16; off <<= 1) {
            ps += __shfl_xor(ps, off);
            pd += __shfl_xor(pd, off);
        }
        if (m16 == 0 && rowg < N) { aS2[rowg] = ps; aD2[rowg] = pd; }
    }
}

// ---------------------------------------------------------------------------
// agg2: fused softmax+gather (H=1) over fp8 h2 + bias + log_softmax
// ---------------------------------------------------------------------------
__global__ __launch_bounds__(256) void agg2_kernel(
    const unsigned char* __restrict__ h2f, const float* __restrict__ aS2,
    const float* __restrict__ aD2, const int* __restrict__ offsets,
    const int* __restrict__ csr_src, const float* __restrict__ b2,
    float* __restrict__ out, int N)
{
    int lane = threadIdx.x & 63, wid = threadIdx.x >> 6;
    int n = blockIdx.x * 4 + wid;
    if (n >= N) return;
    int start = offsets[n], end = offsets[n + 1];
    bool act = lane < OUTC;
    int cc = act ? lane : 0;
    float ad = aD2[n];

    float acc = 0.f, denom = 0.f;
    int p = start;
    for (; p + 4 <= end; p += 4) {
        int s0 = csr_src[p], s1 = csr_src[p + 1], s2 = csr_src[p + 2], s3 = csr_src[p + 3];
        float w0 = __expf(leaky(aS2[s0] + ad));
        float w1 = __expf(leaky(aS2[s1] + ad));
        float w2 = __expf(leaky(aS2[s2] + ad));
        float w3 = __expf(leaky(aS2[s3] + ad));
        unsigned char v0 = h2f[(size_t)s0 * OUTC + cc];
        unsigned char v1 = h2f[(size_t)s1 * OUTC + cc];
        unsigned char v2 = h2f[(size_t)s2 * OUTC + cc];
        unsigned char v3 = h2f[(size_t)s3 * OUTC + cc];
        denom += w0 + w1 + w2 + w3;
        acc += w0 * fp8_to_f32(v0) + w1 * fp8_to_f32(v1)
             + w2 * fp8_to_f32(v2) + w3 * fp8_to_f32(v3);
    }
    for (; p < end; ++p) {
        int s = csr_src[p];
        float w = __expf(leaky(aS2[s] + ad));
        denom += w;
        acc += w * fp8_to_f32(h2f[(size_t)s * OUTC + cc]);
    }

    float v = acc / (denom + EPSV) + (act ? b2[lane] : 0.f);

    float vm = act ? v : -INFINITY;
#pragma unroll
    for (int off = 32; off > 0; off >>= 1) vm = fmaxf(vm, __shfl_xor(vm, off));
    float ex2 = act ? __expf(v - vm) : 0.f;
    float tot = ex2;
#pragma unroll
    for (int off = 32; off > 0; off >>= 1) tot += __shfl_xor(tot, off);
    float res = v - vm - __logf(tot);
    if (act) out[(size_t)n * OUTC + lane] = res;
}

// ---------------------------------------------------------------------------
extern "C" void kernel_launch(void* const* d_in, const int* in_sizes, int n_in,
                              void* d_out, int out_size, void* d_ws, size_t ws_size,
                              hipStream_t stream)
{
    const float* x     = (const float*)d_in[0];
    const int*   ei    = (const int*)d_in[1];
    const float* W1    = (const float*)d_in[2];
    const float* attS1 = (const float*)d_in[3];
    const float* attD1 = (const float*)d_in[4];
    const float* b1    = (const float*)d_in[5];
    const float* W2    = (const float*)d_in[6];
    const float* attS2 = (const float*)d_in[7];
    const float* attD2 = (const float*)d_in[8];
    const float* b2    = (const float*)d_in[9];
    float* out = (float*)d_out;

    const int N    = in_sizes[0] / FIN;
    const int E    = in_sizes[1] / 2;
    const int Etot = E + N;
    const int nb   = (N + 1023) / 1024;

    char* ws = (char*)d_ws;
    size_t off = 0;
    auto take = [&](size_t bytes) -> char* {
        char* p = ws + off;
        off = (off + bytes + 255) & ~(size_t)255;
        return p;
    };
    unsigned char* h1f = (unsigned char*)take((size_t)N * H1DIM);
    short* g1b     = (short*)take((size_t)N * H1DIM * 2);
    short* w1t     = (short*)take((size_t)FIN * H1DIM * 2);
    short* w2t     = (short*)take((size_t)48 * 256 * 2);
    float* aS1     = (float*)take((size_t)N * 4 * 4);
    float* aD1     = (float*)take((size_t)N * 4 * 4);
    unsigned char* h2f = (unsigned char*)take((size_t)N * OUTC);
    float* aS2v    = (float*)take((size_t)N * 4);
    float* aD2v    = (float*)take((size_t)N * 4);
    int*   deg     = (int*)take((size_t)N * 4);
    int*   offsets = (int*)take((size_t)(N + 1) * 4);
    int*   bsums   = (int*)take((size_t)nb * 4);
    int*   boffs   = (int*)take((size_t)nb * 4);
    int*   rank    = (int*)take((size_t)Etot * 4);
    int*   csr_src = (int*)take((size_t)Etot * 4);

    (void)hipMemsetAsync(deg, 0, (size_t)N * 4, stream);

    cvt_w1_kernel<<<(FIN * H1DIM + 255) / 256, 256, 0, stream>>>(W1, w1t);
    cvt_w2_kernel<<<48, 256, 0, stream>>>(W2, w2t);
    gemm1_mfma_kernel<<<(N + 127) / 128, 256, 0, stream>>>(x, w1t, attS1, attD1, h1f, aS1, aD1, N);
    degcount_kernel<<<(Etot + 255) / 256, 256, 0, stream>>>(ei, deg, rank, E, Etot);
    scan_partial_kernel<<<nb, 1024, 0, stream>>>(deg, offsets, bsums, N);
    scan_tops_kernel<<<1, 1024, 0, stream>>>(bsums, boffs, nb);
    scan_add_kernel<<<nb, 1024, 0, stream>>>(offsets, boffs, N);
    scatter_kernel<<<(Etot + 255) / 256, 256, 0, stream>>>(ei, offsets, rank, csr_src, E, Etot);
    agg1_kernel<<<(N + 3) / 4, 256, 0, stream>>>(h1f, aS1, aD1, offsets, csr_src, b1, g1b, N);
    gemm2_kernel<<<(N + 63) / 64, 256, 0, stream>>>(g1b, w2t, attS2, attD2, h2f, aS2v, aD2v, N);
    agg2_kernel<<<(N + 3) / 4, 256, 0, stream>>>(h2f, aS2v, aD2v, offsets, csr_src, b2, out, N);
}

// Round 12
// 352.054 us; speedup vs baseline: 1.4332x; 1.0044x over previous
//
#include <hip/hip_runtime.h>
#include <math.h>

#define FIN   512
#define H1DIM 256
#define HEADS 4
#define CH    64
#define OUTC  40
#define NEG   0.2f
#define EPSV  1e-16f
#define BK    64

// leaky_relu(a) = max(a, 0.2a)  (valid for all a since 0 < slope < 1): mul+max
__device__ __forceinline__ float leaky(float a) { return fmaxf(a, NEG * a); }

__device__ __forceinline__ short f2bf(float f) {
    unsigned u = __builtin_bit_cast(unsigned, f);
    u += 0x7FFFu + ((u >> 16) & 1u);
    return (short)(u >> 16);
}
__device__ __forceinline__ float bf2f(short s) {
    return __builtin_bit_cast(float, ((unsigned)(unsigned short)s) << 16);
}
// packed f32->bf16 (RNE): 2 elements / instruction
__device__ __forceinline__ unsigned cvtpk(float lo, float hi) {
    unsigned r;
    asm("v_cvt_pk_bf16_f32 %0, %1, %2" : "=v"(r) : "v"(lo), "v"(hi));
    return r;
}

typedef __attribute__((ext_vector_type(2))) float floatx2;

// fp8 (OCP e4m3) HW conversions. Word-select must be an immediate constant.
__device__ __forceinline__ unsigned f32x2_to_fp8x2(float a, float b) {
    return (unsigned)__builtin_amdgcn_cvt_pk_fp8_f32(a, b, 0, false);
}
template <bool HI>
__device__ __forceinline__ floatx2 fp8x2_to_f32(unsigned u) {
    return __builtin_amdgcn_cvt_pk_f32_fp8((int)u, HI);
}
__device__ __forceinline__ float fp8_to_f32(unsigned char b) {
    return fp8x2_to_f32<false>((unsigned)b).x;
}

typedef __attribute__((ext_vector_type(8))) short short8;
typedef __attribute__((ext_vector_type(4))) short short4_t;
typedef __attribute__((ext_vector_type(4))) float float4_t;

typedef unsigned int u32;
typedef const __attribute__((address_space(1))) u32 gu32;
typedef __attribute__((address_space(3))) u32 lu32;

__device__ __forceinline__ void load_lds16(const void* g, void* l) {
    __builtin_amdgcn_global_load_lds((gu32*)g, (lu32*)l, 16, 0, 0);
}

// ---------------------------------------------------------------------------
// W1 [512,256] fp32 -> w1t [256,512] bf16 (transposed), plus
// W2 [256,40] f32 -> w2t [48][256] bf16 (transposed, zero-padded cols 40..47)
// fused into one launch (grid covers both ranges).
// ---------------------------------------------------------------------------
__global__ void cvt_w_kernel(const float* __restrict__ W1, short* __restrict__ w1t,
                             const float* __restrict__ W2, short* __restrict__ w2t)
{
    int idx = blockIdx.x * 256 + threadIdx.x;
    if (idx < FIN * H1DIM) {
        int k = idx >> 8;
        int n = idx & 255;
        w1t[(size_t)n * FIN + k] = f2bf(W1[idx]);
    }
    int idx2 = idx - FIN * H1DIM;
    if (idx2 >= 0 && idx2 < 48 * 256) {
        int col = idx2 >> 8;
        int k   = idx2 & 255;
        float v = (col < OUTC) ? W2[(size_t)k * OUTC + col] : 0.f;
        w2t[idx2] = f2bf(v);
    }
}

// ---------------------------------------------------------------------------
// GEMM1 (MFMA bf16) + fused attention scores.
// 128-row tile, coalesced global_load_lds A staging (proven), 2-barrier loop.
// B read per-lane straight from L2-resident w1t (256 KB): deletes the B LDS
// tile (64->32 KB LDS) and half the per-K-step staging/drain. bounds(256,2)
// allows 256 VGPR -> no spill (R5/R10's probes were spill-contaminated).
// Epilogue bounces fp8 h1 through the A-LDS buffer for coalesced stores.
// ---------------------------------------------------------------------------
__global__ __launch_bounds__(256, 2) void gemm1_mfma_kernel(
    const float* __restrict__ x, const short* __restrict__ w1t,
    const float* __restrict__ attS, const float* __restrict__ attD,
    unsigned char* __restrict__ h1f, float* __restrict__ aS1, float* __restrict__ aD1, int N)
{
    __shared__ float Alf[128 * BK];   // 32KB fp32 A-tile

    const int tid  = threadIdx.x;
    const int lane = tid & 63;
    const int wid  = tid >> 6;
    const int row0 = blockIdx.x * 128;
    const int col0 = wid * 64;
    const int quad = lane >> 4;
    const int m16  = lane & 15;

    const int achunk = ((tid & 15) ^ (tid >> 4)) * 4;
    const float* asrcA[8];
#pragma unroll
    for (int p = 0; p < 8; ++p) {
        int r = row0 + p * 16 + (tid >> 4);
        if (r >= N) r = N - 1;
        asrcA[p] = x + (size_t)r * FIN + achunk;
    }

    // B per-lane column pointers into L2-resident w1t
    const short* bp[4];
#pragma unroll
    for (int j = 0; j < 4; ++j)
        bp[j] = w1t + (size_t)(col0 + j * 16 + m16) * FIN + quad * 8;

    float4_t acc[8][4];
#pragma unroll
    for (int i = 0; i < 8; ++i)
#pragma unroll
        for (int j = 0; j < 4; ++j) acc[i][j] = (float4_t){0.f, 0.f, 0.f, 0.f};

    for (int k0 = 0; k0 < FIN; k0 += BK) {
#pragma unroll
        for (int p = 0; p < 8; ++p)
            load_lds16(asrcA[p] + k0, Alf + p * 1024 + tid * 4);

        // B fragments for this K-step (8 x 16B, L2-hit), issued before the
        // barrier so their latency overlaps the stage drain
        short8 b[2][4];
#pragma unroll
        for (int half = 0; half < 2; ++half)
#pragma unroll
            for (int j = 0; j < 4; ++j)
                b[half][j] = *(const short8*)(bp[j] + k0 + half * 32);

        __syncthreads();

#pragma unroll
        for (int half = 0; half < 2; ++half) {
#pragma unroll
            for (int i = 0; i < 8; ++i) {
                int row = i * 16 + m16;
                int c0 = (quad + 4 * half) * 2;
                float4 f0 = *(const float4*)&Alf[row * BK + ((c0 ^ m16) * 4)];
                float4 f1 = *(const float4*)&Alf[row * BK + (((c0 + 1) ^ m16) * 4)];
                short8 a;
                unsigned* tp = (unsigned*)&a;
                tp[0] = cvtpk(f0.x, f0.y);
                tp[1] = cvtpk(f0.z, f0.w);
                tp[2] = cvtpk(f1.x, f1.y);
                tp[3] = cvtpk(f1.z, f1.w);
#pragma unroll
                for (int j = 0; j < 4; ++j)
                    acc[i][j] = __builtin_amdgcn_mfma_f32_16x16x32_bf16(a, b[half][j], acc[i][j], 0, 0, 0);
            }
        }
        __syncthreads();
    }

    float attSv[4], attDv[4];
#pragma unroll
    for (int j = 0; j < 4; ++j) {
        attSv[j] = attS[col0 + j * 16 + m16];
        attDv[j] = attD[col0 + j * 16 + m16];
    }

    // epilogue: bounce fp8 through Alf (32 KB = 128 rows x 256 B exactly)
    unsigned char* Bounce = (unsigned char*)Alf;

#pragma unroll
    for (int i = 0; i < 8; ++i) {
#pragma unroll
        for (int r = 0; r < 4; ++r) {
            int rloc = i * 16 + quad * 4 + r;
            unsigned pa = f32x2_to_fp8x2(acc[i][0][r], acc[i][1][r]);
            unsigned pb = f32x2_to_fp8x2(acc[i][2][r], acc[i][3][r]);
            int cb = rloc * 256 + col0 + m16;
            Bounce[cb]      = (unsigned char)(pa & 0xff);
            Bounce[cb + 16] = (unsigned char)((pa >> 8) & 0xff);
            Bounce[cb + 32] = (unsigned char)(pb & 0xff);
            Bounce[cb + 48] = (unsigned char)((pb >> 8) & 0xff);

            float ps = acc[i][0][r] * attSv[0] + acc[i][1][r] * attSv[1]
                     + acc[i][2][r] * attSv[2] + acc[i][3][r] * attSv[3];
            float pd = acc[i][0][r] * attDv[0] + acc[i][1][r] * attDv[1]
                     + acc[i][2][r] * attDv[2] + acc[i][3][r] * attDv[3];
#pragma unroll
            for (int off = 1; off < 16; off <<= 1) {
                ps += __shfl_xor(ps, off);
                pd += __shfl_xor(pd, off);
            }
            int row = row0 + rloc;
            if (m16 == 0 && row < N) {
                aS1[(size_t)row * 4 + wid] = ps;
                aD1[(size_t)row * 4 + wid] = pd;
            }
        }
    }
    __syncthreads();

    // coalesced writeback: 32 KB, 16B/lane full-line stores
#pragma unroll
    for (int inst = 0; inst < 8; ++inst) {
        int flat = inst * 4096 + tid * 16;
        int row  = flat >> 8;
        if (row0 + row < N)
            *(float4*)(h1f + (size_t)row0 * H1DIM + flat) = *(const float4*)(Bounce + flat);
    }
}

// ---------------------------------------------------------------------------
// CSR build. degcount returns per-edge rank (atomic return value) so scatter
// needs no second atomic pass.
// ---------------------------------------------------------------------------
__global__ void degcount_kernel(const int* __restrict__ ei, int* __restrict__ deg,
                                int* __restrict__ rank, int E, int Etot)
{
    int e = blockIdx.x * 256 + threadIdx.x;
    if (e >= Etot) return;
    int d = (e < E) ? ei[E + e] : (e - E);
    rank[e] = atomicAdd(&deg[d], 1);
}

__global__ __launch_bounds__(1024) void scan_partial_kernel(
    const int* __restrict__ deg, int* __restrict__ offsets,
    int* __restrict__ bsums, int N)
{
    __shared__ int wsums[16];
    __shared__ int excl[16];
    int tid = threadIdx.x, lane = tid & 63, wid = tid >> 6;
    int idx = blockIdx.x * 1024 + tid;
    int v = (idx < N) ? deg[idx] : 0;
    int sv = v;
#pragma unroll
    for (int off = 1; off < 64; off <<= 1) {
        int t = __shfl_up(sv, off, 64);
        if (lane >= off) sv += t;
    }
    if (lane == 63) wsums[wid] = sv;
    __syncthreads();
    if (wid == 0 && lane < 16) {
        int wv = wsums[lane];
        int sw = wv;
#pragma unroll
        for (int off = 1; off < 16; off <<= 1) {
            int t = __shfl_up(sw, off, 64);
            if (lane >= off) sw += t;
        }
        excl[lane] = sw - wv;
        if (lane == 15) bsums[blockIdx.x] = sw;
    }
    __syncthreads();
    if (idx < N) offsets[idx + 1] = sv + excl[wid];
}

__global__ __launch_bounds__(1024) void scan_tops_kernel(
    int* __restrict__ bsums, int* __restrict__ boffs, int nb)
{
    __shared__ int wsums[16];
    __shared__ int excl[16];
    int tid = threadIdx.x, lane = tid & 63, wid = tid >> 6;
    int v = (tid < nb) ? bsums[tid] : 0;
    int sv = v;
#pragma unroll
    for (int off = 1; off < 64; off <<= 1) {
        int t = __shfl_up(sv, off, 64);
        if (lane >= off) sv += t;
    }
    if (lane == 63) wsums[wid] = sv;
    __syncthreads();
    if (wid == 0 && lane < 16) {
        int wv = wsums[lane];
        int sw = wv;
#pragma unroll
        for (int off = 1; off < 16; off <<= 1) {
            int t = __shfl_up(sw, off, 64);
            if (lane >= off) sw += t;
        }
        excl[lane] = sw - wv;
    }
    __syncthreads();
    if (tid < nb) boffs[tid] = sv + excl[wid] - v;
}

__global__ __launch_bounds__(1024) void scan_add_kernel(
    int* __restrict__ offsets, const int* __restrict__ boffs, int N)
{
    int idx = blockIdx.x * 1024 + threadIdx.x;
    if (idx == 0) offsets[0] = 0;
    if (idx < N) offsets[idx + 1] += boffs[blockIdx.x];
}

__global__ void scatter_kernel(const int* __restrict__ ei, const int* __restrict__ offsets,
                               const int* __restrict__ rank, int* __restrict__ csr_src,
                               int E, int Etot)
{
    int e = blockIdx.x * 256 + threadIdx.x;
    if (e >= Etot) return;
    int s, d;
    if (e < E) { s = ei[e]; d = ei[E + e]; }
    else       { s = e - E; d = s; }
    csr_src[offsets[d] + rank[e]] = s;
}

// ---------------------------------------------------------------------------
// agg1: fused softmax+gather over fp8 h1 rows (256B each). Wave split into
// two 32-lane halves, each half handles one edge of a pair with 8B/lane
// (uint2) row loads + HW fp8 decode. g1b = ELU(acc/denom + b1), bf16.
// ---------------------------------------------------------------------------
__global__ __launch_bounds__(256) void agg1_kernel(
    const unsigned char* __restrict__ h1f, const float* __restrict__ aS,
    const float* __restrict__ aD, const int* __restrict__ offsets,
    const int* __restrict__ csr_src, const float* __restrict__ b1,
    short* __restrict__ g1b, int N)
{
    int lane = threadIdx.x & 63, wid = threadIdx.x >> 6;
    int half = lane >> 5;          // which edge of the pair this lane serves
    int l32  = lane & 31;
    int n = blockIdx.x * 4 + wid;
    if (n >= N) return;
    int start = offsets[n], end = offsets[n + 1];
    int h = l32 >> 3;              // head = channel/64, 8 channels per lane
    int cbase = l32 * 8;
    float adh = aD[(size_t)n * 4 + h];

    float ac[8];
#pragma unroll
    for (int c = 0; c < 8; ++c) ac[c] = 0.f;
    float denom = 0.f;

    int p = start;
    for (; p + 4 <= end; p += 4) {
        int sA0 = csr_src[p],     sB0 = csr_src[p + 1];
        int sA1 = csr_src[p + 2], sB1 = csr_src[p + 3];
        int s0 = half ? sB0 : sA0;
        int s1 = half ? sB1 : sA1;
        float t0 = aS[(size_t)s0 * 4 + h] + adh;
        float t1 = aS[(size_t)s1 * 4 + h] + adh;
        uint2 r0 = *(const uint2*)&h1f[(size_t)s0 * H1DIM + cbase];
        uint2 r1 = *(const uint2*)&h1f[(size_t)s1 * H1DIM + cbase];
        float w0 = __expf(leaky(t0));
        float w1 = __expf(leaky(t1));
        denom += w0 + w1;
        floatx2 d0a = fp8x2_to_f32<false>(r0.x), d0b = fp8x2_to_f32<true>(r0.x);
        floatx2 d0c = fp8x2_to_f32<false>(r0.y), d0d = fp8x2_to_f32<true>(r0.y);
        floatx2 d1a = fp8x2_to_f32<false>(r1.x), d1b = fp8x2_to_f32<true>(r1.x);
        floatx2 d1c = fp8x2_to_f32<false>(r1.y), d1d = fp8x2_to_f32<true>(r1.y);
        ac[0] += w0 * d0a.x + w1 * d1a.x;
        ac[1] += w0 * d0a.y + w1 * d1a.y;
        ac[2] += w0 * d0b.x + w1 * d1b.x;
        ac[3] += w0 * d0b.y + w1 * d1b.y;
        ac[4] += w0 * d0c.x + w1 * d1c.x;
        ac[5] += w0 * d0c.y + w1 * d1c.y;
        ac[6] += w0 * d0d.x + w1 * d1d.x;
        ac[7] += w0 * d0d.y + w1 * d1d.y;
    }
    for (; p + 2 <= end; p += 2) {
        int sA = csr_src[p], sB = csr_src[p + 1];
        int s = half ? sB : sA;
        float t = aS[(size_t)s * 4 + h] + adh;
        uint2 r = *(const uint2*)&h1f[(size_t)s * H1DIM + cbase];
        float w = __expf(leaky(t));
        denom += w;
        floatx2 da = fp8x2_to_f32<false>(r.x), db = fp8x2_to_f32<true>(r.x);
        floatx2 dc = fp8x2_to_f32<false>(r.y), dd = fp8x2_to_f32<true>(r.y);
        ac[0] += w * da.x; ac[1] += w * da.y;
        ac[2] += w * db.x; ac[3] += w * db.y;
        ac[4] += w * dc.x; ac[5] += w * dc.y;
        ac[6] += w * dd.x; ac[7] += w * dd.y;
    }
    if (p < end) {   // odd tail: both halves read same edge, half 1 gated to 0
        int s = csr_src[p];
        float t = aS[(size_t)s * 4 + h] + adh;
        uint2 r = *(const uint2*)&h1f[(size_t)s * H1DIM + cbase];
        float w = half ? 0.f : __expf(leaky(t));
        denom += w;
        floatx2 da = fp8x2_to_f32<false>(r.x), db = fp8x2_to_f32<true>(r.x);
        floatx2 dc = fp8x2_to_f32<false>(r.y), dd = fp8x2_to_f32<true>(r.y);
        ac[0] += w * da.x; ac[1] += w * da.y;
        ac[2] += w * db.x; ac[3] += w * db.y;
        ac[4] += w * dc.x; ac[5] += w * dc.y;
        ac[6] += w * dd.x; ac[7] += w * dd.y;
    }

    // combine the two half-wave partial sums
    denom += __shfl_xor(denom, 32);
#pragma unroll
    for (int c = 0; c < 8; ++c) ac[c] += __shfl_xor(ac[c], 32);

    if (half == 0) {
        float inv = 1.f / (denom + EPSV);
        float4 b0 = *(const float4*)&b1[cbase];
        float4 b4 = *(const float4*)&b1[cbase + 4];
        float v[8];
        v[0] = ac[0] * inv + b0.x;
        v[1] = ac[1] * inv + b0.y;
        v[2] = ac[2] * inv + b0.z;
        v[3] = ac[3] * inv + b0.w;
        v[4] = ac[4] * inv + b4.x;
        v[5] = ac[5] * inv + b4.y;
        v[6] = ac[6] * inv + b4.z;
        v[7] = ac[7] * inv + b4.w;
#pragma unroll
        for (int c = 0; c < 8; ++c) v[c] = v[c] > 0.f ? v[c] : expm1f(v[c]);
        short8 o;
        unsigned* op = (unsigned*)&o;
        op[0] = cvtpk(v[0], v[1]);
        op[1] = cvtpk(v[2], v[3]);
        op[2] = cvtpk(v[4], v[5]);
        op[3] = cvtpk(v[6], v[7]);
        *(short8*)&g1b[(size_t)n * H1DIM + cbase] = o;
    }
}

// ---------------------------------------------------------------------------
// GEMM2 (MFMA bf16): h2f[N,40] fp8 = g1[N,256] @ W2; fused a_src2/a_dst2.
// h2 stored fp8 e4m3: 2 MB -> L2-resident in every XCD for agg2's gathers.
// ---------------------------------------------------------------------------
__global__ __launch_bounds__(256, 4) void gemm2_kernel(
    const short* __restrict__ g1b, const short* __restrict__ w2t,
    const float* __restrict__ attS2, const float* __restrict__ attD2,
    unsigned char* __restrict__ h2f, float* __restrict__ aS2, float* __restrict__ aD2, int N)
{
    __shared__ short As[64 * 256];   // 32 KB bf16 A-tile, chunk-swizzled

    const int tid  = threadIdx.x;
    const int lane = tid & 63;
    const int wid  = tid >> 6;
    const int row0 = blockIdx.x * 64;
    const int quad = lane >> 4;
    const int m16  = lane & 15;

    // stage: 8 x 16B per thread; source chunk XOR-swizzled so the strided
    // column reads below are conflict-free (LDS dest stays linear)
#pragma unroll
    for (int p = 0; p < 8; ++p) {
        int f    = p * 256 + tid;        // 16B-chunk index 0..2047
        int row  = f >> 5;               // 32 chunks per row
        int cpos = f & 31;
        int csrc = cpos ^ (row & 15);
        int gr = row0 + row; if (gr >= N) gr = N - 1;
        load_lds16(g1b + (size_t)gr * H1DIM + csrc * 8, (char*)As + (size_t)f * 16);
    }
    __syncthreads();

    const short* bp[3];
#pragma unroll
    for (int j = 0; j < 3; ++j)
        bp[j] = w2t + (j * 16 + m16) * 256 + quad * 8;

    float4_t acc[3];
#pragma unroll
    for (int j = 0; j < 3; ++j) acc[j] = (float4_t){0.f, 0.f, 0.f, 0.f};

    const int wrow = wid * 16;
#pragma unroll
    for (int kk = 0; kk < 8; ++kk) {
        short8 a = *(const short8*)&As[(wrow + m16) * 256 + (((kk * 4 + quad) ^ m16) * 8)];
        short8 b0 = *(const short8*)(bp[0] + kk * 32);
        short8 b1v = *(const short8*)(bp[1] + kk * 32);
        short8 b2v = *(const short8*)(bp[2] + kk * 32);
        acc[0] = __builtin_amdgcn_mfma_f32_16x16x32_bf16(a, b0, acc[0], 0, 0, 0);
        acc[1] = __builtin_amdgcn_mfma_f32_16x16x32_bf16(a, b1v, acc[1], 0, 0, 0);
        acc[2] = __builtin_amdgcn_mfma_f32_16x16x32_bf16(a, b2v, acc[2], 0, 0, 0);
    }

    float attSv[3], attDv[3];
#pragma unroll
    for (int j = 0; j < 3; ++j) {
        int col = j * 16 + m16;
        attSv[j] = (col < OUTC) ? attS2[col] : 0.f;
        attDv[j] = (col < OUTC) ? attD2[col] : 0.f;
    }

#pragma unroll
    for (int r = 0; r < 4; ++r) {
        int rowg = row0 + wrow + quad * 4 + r;
        if (rowg < N) {
#pragma unroll
            for (int j = 0; j < 3; ++j) {
                int col = j * 16 + m16;
                if (col < OUTC)
                    h2f[(size_t)rowg * OUTC + col] =
                        (unsigned char)(f32x2_to_fp8x2(acc[j][r], 0.f) & 0xff);
            }
        }
        float ps = acc[0][r] * attSv[0] + acc[1][r] * attSv[1] + acc[2][r] * attSv[2];
        float pd = acc[0][r] * attDv[0] + acc[1][r] * attDv[1] + acc[2][r] * attDv[2];
#pragma unroll
        for (int off = 1; off < 16; off <<= 1) {
            ps += __shfl_xor(ps, off);
            pd += __shfl_xor(pd, off);
        }
        if (m16 == 0 && rowg < N) { aS2[rowg] = ps; aD2[rowg] = pd; }
    }
}

// ---------------------------------------------------------------------------
// agg2: fused softmax+gather (H=1) over fp8 h2 + bias + log_softmax
// ---------------------------------------------------------------------------
__global__ __launch_bounds__(256) void agg2_kernel(
    const unsigned char* __restrict__ h2f, const float* __restrict__ aS2,
    const float* __restrict__ aD2, const int* __restrict__ offsets,
    const int* __restrict__ csr_src, const float* __restrict__ b2,
    float* __restrict__ out, int N)
{
    int lane = threadIdx.x & 63, wid = threadIdx.x >> 6;
    int n = blockIdx.x * 4 + wid;
    if (n >= N) return;
    int start = offsets[n], end = offsets[n + 1];
    bool act = lane < OUTC;
    int cc = act ? lane : 0;
    float ad = aD2[n];

    float acc = 0.f, denom = 0.f;
    int p = start;
    for (; p + 4 <= end; p += 4) {
        int s0 = csr_src[p], s1 = csr_src[p + 1], s2 = csr_src[p + 2], s3 = csr_src[p + 3];
        float w0 = __expf(leaky(aS2[s0] + ad));
        float w1 = __expf(leaky(aS2[s1] + ad));
        float w2 = __expf(leaky(aS2[s2] + ad));
        float w3 = __expf(leaky(aS2[s3] + ad));
        unsigned char v0 = h2f[(size_t)s0 * OUTC + cc];
        unsigned char v1 = h2f[(size_t)s1 * OUTC + cc];
        unsigned char v2 = h2f[(size_t)s2 * OUTC + cc];
        unsigned char v3 = h2f[(size_t)s3 * OUTC + cc];
        denom += w0 + w1 + w2 + w3;
        acc += w0 * fp8_to_f32(v0) + w1 * fp8_to_f32(v1)
             + w2 * fp8_to_f32(v2) + w3 * fp8_to_f32(v3);
    }
    for (; p < end; ++p) {
        int s = csr_src[p];
        float w = __expf(leaky(aS2[s] + ad));
        denom += w;
        acc += w * fp8_to_f32(h2f[(size_t)s * OUTC + cc]);
    }

    float v = acc / (denom + EPSV) + (act ? b2[lane] : 0.f);

    float vm = act ? v : -INFINITY;
#pragma unroll
    for (int off = 32; off > 0; off >>= 1) vm = fmaxf(vm, __shfl_xor(vm, off));
    float ex2 = act ? __expf(v - vm) : 0.f;
    float tot = ex2;
#pragma unroll
    for (int off = 32; off > 0; off >>= 1) tot += __shfl_xor(tot, off);
    float res = v - vm - __logf(tot);
    if (act) out[(size_t)n * OUTC + lane] = res;
}

// ---------------------------------------------------------------------------
extern "C" void kernel_launch(void* const* d_in, const int* in_sizes, int n_in,
                              void* d_out, int out_size, void* d_ws, size_t ws_size,
                              hipStream_t stream)
{
    const float* x     = (const float*)d_in[0];
    const int*   ei    = (const int*)d_in[1];
    const float* W1    = (const float*)d_in[2];
    const float* attS1 = (const float*)d_in[3];
    const float* attD1 = (const float*)d_in[4];
    const float* b1    = (const float*)d_in[5];
    const float* W2    = (const float*)d_in[6];
    const float* attS2 = (const float*)d_in[7];
    const float* attD2 = (const float*)d_in[8];
    const float* b2    = (const float*)d_in[9];
    float* out = (float*)d_out;

    const int N    = in_sizes[0] / FIN;
    const int E    = in_sizes[1] / 2;
    const int Etot = E + N;
    const int nb   = (N + 1023) / 1024;

    char* ws = (char*)d_ws;
    size_t off = 0;
    auto take = [&](size_t bytes) -> char* {
        char* p = ws + off;
        off = (off + bytes + 255) & ~(size_t)255;
        return p;
    };
    unsigned char* h1f = (unsigned char*)take((size_t)N * H1DIM);
    short* g1b     = (short*)take((size_t)N * H1DIM * 2);
    short* w1t     = (short*)take((size_t)FIN * H1DIM * 2);
    short* w2t     = (short*)take((size_t)48 * 256 * 2);
    float* aS1     = (float*)take((size_t)N * 4 * 4);
    float* aD1     = (float*)take((size_t)N * 4 * 4);
    unsigned char* h2f = (unsigned char*)take((size_t)N * OUTC);
    float* aS2v    = (float*)take((size_t)N * 4);
    float* aD2v    = (float*)take((size_t)N * 4);
    int*   deg     = (int*)take((size_t)N * 4);
    int*   offsets = (int*)take((size_t)(N + 1) * 4);
    int*   bsums   = (int*)take((size_t)nb * 4);
    int*   boffs   = (int*)take((size_t)nb * 4);
    int*   rank    = (int*)take((size_t)Etot * 4);
    int*   csr_src = (int*)take((size_t)Etot * 4);

    (void)hipMemsetAsync(deg, 0, (size_t)N * 4, stream);

    cvt_w_kernel<<<(FIN * H1DIM + 48 * 256 + 255) / 256, 256, 0, stream>>>(W1, w1t, W2, w2t);
    gemm1_mfma_kernel<<<(N + 127) / 128, 256, 0, stream>>>(x, w1t, attS1, attD1, h1f, aS1, aD1, N);
    degcount_kernel<<<(Etot + 255) / 256, 256, 0, stream>>>(ei, deg, rank, E, Etot);
    scan_partial_kernel<<<nb, 1024, 0, stream>>>(deg, offsets, bsums, N);
    scan_tops_kernel<<<1, 1024, 0, stream>>>(bsums, boffs, nb);
    scan_add_kernel<<<nb, 1024, 0, stream>>>(offsets, boffs, N);
    scatter_kernel<<<(Etot + 255) / 256, 256, 0, stream>>>(ei, offsets, rank, csr_src, E, Etot);
    agg1_kernel<<<(N + 3) / 4, 256, 0, stream>>>(h1f, aS1, aD1, offsets, csr_src, b1, g1b, N);
    gemm2_kernel<<<(N + 63) / 64, 256, 0, stream>>>(g1b, w2t, attS2, attD2, h2f, aS2v, aD2v, N);
    agg2_kernel<<<(N + 3) / 4, 256, 0, stream>>>(h2f, aS2v, aD2v, offsets, csr_src, b2, out, N);
}